// Round 8
// baseline (480.779 us; speedup 1.0000x reference)
//
#include <hip/hip_runtime.h>
#include <math.h>

typedef float f32x4 __attribute__((ext_vector_type(4)));
typedef __bf16 bf16x8 __attribute__((ext_vector_type(8)));
typedef __bf16 bf16x4 __attribute__((ext_vector_type(4)));

// Problem constants
static constexpr int NB = 2, NT = 2048, NC = 1024, NH = 16, ND = 64;
static constexpr int NM = NB * NT;   // 4096 rows

__device__ inline float rdlane(float v, int l) {
  return __builtin_bit_cast(float, __builtin_amdgcn_readlane(__builtin_bit_cast(int, v), l));
}

// ---------------------------------------------------------------------------
// fp32 -> bf16 convert (vectorized x4)
__global__ __launch_bounds__(256) void k_convert(const float* __restrict__ src,
                                                 __bf16* __restrict__ dst, int n4) {
  int i = blockIdx.x * 256 + threadIdx.x;
  if (i >= n4) return;
  float4 v = ((const float4*)src)[i];
  bf16x4 o;
  o.x = (__bf16)v.x; o.y = (__bf16)v.y; o.z = (__bf16)v.z; o.w = (__bf16)v.w;
  ((bf16x4*)dst)[i] = o;
}

// ---------------------------------------------------------------------------
// 1024x1024 fp32 [k][n] -> bf16 [n][k] transpose (LDS-tiled, coalesced)
__global__ __launch_bounds__(256) void k_transpose(const float* __restrict__ src,
                                                   __bf16* __restrict__ dst) {
  __shared__ float t[64][65];
  int r0 = blockIdx.y * 64, c0 = blockIdx.x * 64;
  int lr = threadIdx.x >> 6;   // 0..3
  int lc = threadIdx.x & 63;
#pragma unroll
  for (int j = 0; j < 16; j++) {
    int r = j * 4 + lr;
    t[r][lc] = src[(size_t)(r0 + r) * 1024 + c0 + lc];
  }
  __syncthreads();
#pragma unroll
  for (int j = 0; j < 16; j++) {
    int r = j * 4 + lr;
    dst[(size_t)(c0 + r) * 1024 + r0 + lc] = (__bf16)t[lc][r];
  }
}

// ---------------------------------------------------------------------------
// pack [Wgk|Wb]^T (1024x16 each) into 128x1024 bf16 B-tile; rows 32..127 = 0.
// grid 16 (k-tiles of 64), 256 threads.
__global__ __launch_bounds__(256) void k_buildwgb(const float* __restrict__ Wgk,
    const float* __restrict__ Wb, __bf16* __restrict__ wgb_t) {
  int k0 = blockIdx.x * 64;
  int tid = threadIdx.x;
  int n = tid >> 3;            // 0..31
  int kk = (tid & 7) * 8;      // 0..56
  const float* src = n < 16 ? &Wgk[n] : &Wb[n - 16];
#pragma unroll
  for (int i = 0; i < 8; i++) {
    int k = k0 + kk + i;
    wgb_t[(size_t)n * 1024 + k] = (__bf16)src[(size_t)k * 16];
  }
  // zero rows 32..127 (each block zeroes its slice)
  for (int i = tid; i < 6144; i += 256)
    wgb_t[32 * 1024 + (size_t)blockIdx.x * 6144 + i] = (__bf16)0.f;
}

// ---------------------------------------------------------------------------
// bf16 MFMA GEMM: C[M,N] = A[M,1024] @ B^T (B stored [n][k] bf16), fp32 out.
// sel 0..3: 1024-col outputs (nblkPer blocks each); sel 4: 128-col (ldc 128).
__global__ __launch_bounds__(256) void k_gemm(const __bf16* __restrict__ A,
    const __bf16* B0, const __bf16* B1, const __bf16* B2, const __bf16* B3,
    const __bf16* B4, float* C0, float* C1, float* C2, float* C3, float* C4,
    int nblkPer) {
  constexpr int Kd = 1024;
  int mblk = blockIdx.x;
  int yb = blockIdx.y;
  int sel = yb / nblkPer;
  int nb = yb % nblkPer;
  const __bf16* Bt = sel == 0 ? B0 : sel == 1 ? B1 : sel == 2 ? B2 : sel == 3 ? B3 : B4;
  float* Cp = sel == 0 ? C0 : sel == 1 ? C1 : sel == 2 ? C2 : sel == 3 ? C3 : C4;
  int ldc = sel == 4 ? 128 : 1024;

  __shared__ __bf16 As[128 * 32];
  __shared__ __bf16 Bs[128 * 32];
  int tid = threadIdx.x;
  int lane = tid & 63;
  int w = tid >> 6;
  int wr = w >> 1, wc = w & 1;

  f32x4 acc[4][4];
#pragma unroll
  for (int r = 0; r < 4; r++)
#pragma unroll
    for (int c = 0; c < 4; c++) acc[r][c] = (f32x4){0.f, 0.f, 0.f, 0.f};

  int rowh = tid >> 2;          // 0..63
  int kcol = (tid & 3) * 8;
  const __bf16* aS = A + (size_t)(mblk * 128 + rowh) * Kd + kcol;
  const __bf16* bS = Bt + (size_t)(nb * 128 + rowh) * Kd + kcol;
  int rbase = (wr * 64 + (lane & 15)) * 32 + ((lane >> 4) * 8);
  int cbase = (wc * 64 + (lane & 15)) * 32 + ((lane >> 4) * 8);

  for (int kt = 0; kt < Kd; kt += 32) {
    uint4 a0 = *(const uint4*)(aS + kt);
    uint4 a1 = *(const uint4*)(aS + (size_t)64 * Kd + kt);
    uint4 b0 = *(const uint4*)(bS + kt);
    uint4 b1 = *(const uint4*)(bS + (size_t)64 * Kd + kt);
    __syncthreads();
    *(uint4*)&As[rowh * 32 + kcol] = a0;
    *(uint4*)&As[(rowh + 64) * 32 + kcol] = a1;
    *(uint4*)&Bs[rowh * 32 + kcol] = b0;
    *(uint4*)&Bs[(rowh + 64) * 32 + kcol] = b1;
    __syncthreads();
    bf16x8 af[4], bfr[4];
#pragma unroll
    for (int r = 0; r < 4; r++) af[r] = *(const bf16x8*)&As[rbase + r * 16 * 32];
#pragma unroll
    for (int c = 0; c < 4; c++) bfr[c] = *(const bf16x8*)&Bs[cbase + c * 16 * 32];
#pragma unroll
    for (int r = 0; r < 4; r++)
#pragma unroll
      for (int c = 0; c < 4; c++)
        acc[r][c] = __builtin_amdgcn_mfma_f32_16x16x32_bf16(af[r], bfr[c], acc[r][c], 0, 0, 0);
  }
  int orow = mblk * 128 + wr * 64 + ((lane >> 4) << 2);
  int ocol = nb * 128 + wc * 64 + (lane & 15);
#pragma unroll
  for (int r = 0; r < 4; r++)
#pragma unroll
    for (int c = 0; c < 4; c++)
#pragma unroll
      for (int j = 0; j < 4; j++)
        Cp[(size_t)(orow + r * 16 + j) * ldc + ocol + c * 16] = acc[r][c][j];
}

// ---------------------------------------------------------------------------
// epilogue for gk/beta: pbuf[m][j<32] -> gk_arr/beta_arr [b*16+h][t]
__global__ __launch_bounds__(256) void k_projpost(const float* __restrict__ pbuf,
    const float* __restrict__ bb, const float* __restrict__ A_log,
    const float* __restrict__ dtb, float* __restrict__ gk_arr,
    float* __restrict__ beta_arr) {
  int idx = blockIdx.x * 256 + threadIdx.x;   // 4096*32
  int m = idx >> 5, j = idx & 31;
  int b = m >> 11, t = m & 2047;
  float v = pbuf[(size_t)m * 128 + j];
  if (j < 16) {
    float z = v + dtb[j];
    float sp = z > 20.f ? z : log1pf(__expf(z));
    gk_arr[((size_t)(b * 16 + j)) * 2048 + t] = -__expf(A_log[j]) * sp;
  } else {
    int jj = j - 16;
    float z = v + bb[jj];
    beta_arr[((size_t)(b * 16 + jj)) * 2048 + t] = 1.f / (1.f + __expf(-z));
  }
}

// ---------------------------------------------------------------------------
// depthwise causal conv(K=4) + silu; for q,k additionally l2norm + rope(32).
__global__ __launch_bounds__(256) void k_conv(
    const float* __restrict__ qpre, const float* __restrict__ kpre,
    const float* __restrict__ vpre, const float* __restrict__ cqw,
    const float* __restrict__ ckw, const float* __restrict__ cvw,
    float* __restrict__ qhat, float* __restrict__ khat, float* __restrict__ vhat) {
  int z = blockIdx.z;
  const float* src = z == 0 ? qpre : z == 1 ? kpre : vpre;
  const float* cw = z == 0 ? cqw : z == 1 ? ckw : cvw;
  float* dst = z == 0 ? qhat : z == 1 ? khat : vhat;
  int t0 = blockIdx.x * 64;
  int bh = blockIdx.y;
  int b = bh >> 4, h = bh & 15;
  int tid = threadIdx.x;
  __shared__ float tile[67 * 64];
  __shared__ float outb[64 * 64];
  for (int i = tid; i < 67 * 64; i += 256) {
    int r = i >> 6, c = i & 63;
    int t = t0 - 3 + r;
    tile[i] = (t >= 0) ? src[((size_t)(b * 2048 + t)) * 1024 + h * 64 + c] : 0.f;
  }
  __syncthreads();
  int c = tid & 63;
  int rb = (tid >> 6) * 16;
  float4 w4 = *(const float4*)&cw[(h * 64 + c) * 4];
  size_t obase = ((size_t)bh) * 2048 * 64;
#pragma unroll
  for (int rr = 0; rr < 16; rr++) {
    int r = rb + rr;
    float y = tile[r * 64 + c] * w4.x + tile[(r + 1) * 64 + c] * w4.y +
              tile[(r + 2) * 64 + c] * w4.z + tile[(r + 3) * 64 + c] * w4.w;
    float sv = y * (1.f / (1.f + __expf(-y)));
    if (z == 2) dst[obase + (size_t)(t0 + r) * 64 + c] = sv;
    else outb[r * 64 + c] = sv;
  }
  if (z == 2) return;
  __syncthreads();
  int r = tid >> 2;
  int p = tid & 3;
  float ss = 0.f;
#pragma unroll
  for (int i2 = 0; i2 < 16; i2++) { float vv = outb[r * 64 + p * 16 + i2]; ss += vv * vv; }
  ss += __shfl_xor(ss, 1);
  ss += __shfl_xor(ss, 2);
  float inv = rsqrtf(ss + 1e-6f);
  int tg = t0 + r;
#pragma unroll
  for (int i2 = 0; i2 < 16; i2++) {
    int cc = p * 16 + i2;
    float val = outb[r * 64 + cc] * inv;
    float res;
    if (cc < 16) {
      float x2 = outb[r * 64 + cc + 16] * inv;
      float ang = tg * __expf(-0.5756462732485114f * cc);   // ln(1e4)/16
      float sn, cn; sincosf(ang, &sn, &cn);
      res = val * cn - x2 * sn;
    } else if (cc < 32) {
      float x1 = outb[r * 64 + cc - 16] * inv;
      float ang = tg * __expf(-0.5756462732485114f * (cc - 16));
      float sn, cn; sincosf(ang, &sn, &cn);
      res = val * cn + x1 * sn;
    } else res = val;
    dst[obase + (size_t)tg * 64 + cc] = res;
  }
}

// ---------------------------------------------------------------------------
// Chunked gated-delta, Phase A v2 (parallel, 1024 blocks = bh*32+ch)
__global__ __launch_bounds__(256) void k_chunkA(
    const float* __restrict__ khat, const float* __restrict__ vhat,
    const float* __restrict__ gk_arr, const float* __restrict__ beta_arr,
    float* __restrict__ cumbuf, float* __restrict__ Ubuf, float* __restrict__ Wbuf) {
  int bid = blockIdx.x;
  int bh = bid >> 5, ch = bid & 31;
  int tid = threadIdx.x;
  int lane = tid & 63, w = tid >> 6;
  __shared__ __bf16 Kbf[64 * 64];                         // 8 KB, chunk-swizzled
  __shared__ __attribute__((aligned(16))) float Msh[64 * 68];  // 17.4 KB
  __shared__ float cumsh[64], bsh[64];
  size_t kbase = (size_t)bh * (2048 * 64) + (size_t)ch * 4096;
  size_t gb = (size_t)bh * 2048 + ch * 64;
  size_t cb4096 = (size_t)(bh * 32 + ch) * 4096;

  // --- stage K as bf16, XOR-swizzled (chunk ^= row&7) to kill 128B-row conflicts
  {
    int row = tid >> 2, c16 = (tid & 3) * 16;
    const float* src = &khat[kbase + row * 64 + c16];
    float4 f0 = *(const float4*)(src + 0);
    float4 f1 = *(const float4*)(src + 4);
    float4 f2 = *(const float4*)(src + 8);
    float4 f3 = *(const float4*)(src + 12);
    bf16x8 h0, h1;
    h0[0] = (__bf16)f0.x; h0[1] = (__bf16)f0.y; h0[2] = (__bf16)f0.z; h0[3] = (__bf16)f0.w;
    h0[4] = (__bf16)f1.x; h0[5] = (__bf16)f1.y; h0[6] = (__bf16)f1.z; h0[7] = (__bf16)f1.w;
    h1[0] = (__bf16)f2.x; h1[1] = (__bf16)f2.y; h1[2] = (__bf16)f2.z; h1[3] = (__bf16)f2.w;
    h1[4] = (__bf16)f3.x; h1[5] = (__bf16)f3.y; h1[6] = (__bf16)f3.z; h1[7] = (__bf16)f3.w;
    int ch0 = ((c16 >> 3) + 0) ^ (row & 7);
    int ch1 = ((c16 >> 3) + 1) ^ (row & 7);
    *(bf16x8*)&Kbf[row * 64 + ch0 * 8] = h0;
    *(bf16x8*)&Kbf[row * 64 + ch1 * 8] = h1;
  }
  // --- zero Msh (so substitution can over-read float4 chunks safely)
  for (int i = tid; i < 64 * 68; i += 256) Msh[i] = 0.f;
  // --- g/beta load + wave-parallel inclusive scan (wave 0 only)
  if (tid < 64) {
    float g = gk_arr[gb + tid];
    float bv = beta_arr[gb + tid];
#pragma unroll
    for (int d = 1; d < 64; d <<= 1) {
      float n = __shfl_up(g, d, 64);
      if (tid >= d) g += n;
    }
    cumsh[tid] = g;
    bsh[tid] = bv;
    cumbuf[(size_t)(bh * 32 + ch) * 64 + tid] = g;
  }
  __syncthreads();

  // --- M = tril(K K^T) scaled, via MFMA. wave w owns rows 16w..16w+15.
  {
    f32x4 macc[4];
#pragma unroll
    for (int c = 0; c < 4; c++) macc[c] = (f32x4){0.f, 0.f, 0.f, 0.f};
    int arow = w * 16 + (lane & 15);
    int kb = lane >> 4;
    bf16x8 af0 = *(const bf16x8*)&Kbf[arow * 64 + ((0 + kb) ^ (arow & 7)) * 8];
    bf16x8 af1 = *(const bf16x8*)&Kbf[arow * 64 + ((4 + kb) ^ (arow & 7)) * 8];
#pragma unroll
    for (int c = 0; c < 4; c++) {
      if (c <= w) {
        int brow = c * 16 + (lane & 15);
        bf16x8 bf0 = *(const bf16x8*)&Kbf[brow * 64 + ((0 + kb) ^ (brow & 7)) * 8];
        bf16x8 bf1 = *(const bf16x8*)&Kbf[brow * 64 + ((4 + kb) ^ (brow & 7)) * 8];
        macc[c] = __builtin_amdgcn_mfma_f32_16x16x32_bf16(af0, bf0, macc[c], 0, 0, 0);
        macc[c] = __builtin_amdgcn_mfma_f32_16x16x32_bf16(af1, bf1, macc[c], 0, 0, 0);
      }
    }
    // scale + write lower tiles
    float bt[4], ct[4];
#pragma unroll
    for (int j = 0; j < 4; j++) {
      int trow = w * 16 + (lane >> 4) * 4 + j;
      bt[j] = bsh[trow];
      ct[j] = cumsh[trow];
    }
#pragma unroll
    for (int c = 0; c < 4; c++) {
      if (c <= w) {
        int scol = c * 16 + (lane & 15);
        float cums = cumsh[scol];
#pragma unroll
        for (int j = 0; j < 4; j++) {
          int trow = w * 16 + (lane >> 4) * 4 + j;
          float val = macc[c][j] * bt[j] * __expf(ct[j] - cums);
          Msh[trow * 68 + scol] = (scol < trow) ? val : 0.f;
        }
      }
    }
  }

  // --- RHS columns into registers (threads 0..127: c<64 -> U col, else W col)
  float uw[64];
  int c = tid;
  if (tid < 128) {
    bool isU = c < 64;
    int cc = c & 63;
    const float* src = isU ? &vhat[kbase + cc] : &khat[kbase + cc];
#pragma unroll
    for (int t = 0; t < 64; t++) {
      float r = src[t * 64] * bsh[t];
      if (!isU) r *= __expf(cumsh[t]);
      uw[t] = r;
    }
  }
  __syncthreads();   // Msh ready

  if (tid < 128) {
    // forward substitution, fully in registers; M row chunks broadcast
#pragma unroll
    for (int t = 1; t < 64; t++) {
      float acc = 0.f;
#pragma unroll
      for (int q = 0; q <= (t - 1) >> 2; q++) {
        float4 m4 = *(const float4*)&Msh[t * 68 + q * 4];
        acc += m4.x * uw[q * 4 + 0] + m4.y * uw[q * 4 + 1] +
               m4.z * uw[q * 4 + 2] + m4.w * uw[q * 4 + 3];
      }
      uw[t] -= acc;
    }
    bool isU = c < 64;
    int cc = c & 63;
    float* dst = isU ? &Ubuf[cb4096 + cc] : &Wbuf[cb4096 + cc];
#pragma unroll
    for (int t = 0; t < 64; t++) dst[t * 64] = uw[t];
  }
}

// ---------------------------------------------------------------------------
// Phase B v4 (sequential over chunks, software-pipelined): grid 256.
// bh = bid & 31 so the 8 vb-blocks of one bh share an XCD (L2 co-location);
// __launch_bounds__(256,1) lifts the VGPR cap so the ping-pong register
// pipeline (Wa/Wb + knext) is actually held in registers.
#define CHUNK_STEP(CH, WC, WN, UVC, UVN, CUMC, CUMN, CUR, NXT)                  \
  {                                                                             \
    size_t cb = cbb + (CH);                                                     \
    int chn = (CH) < 31 ? (CH) + 1 : 31;                                        \
    size_t cbn = cbb + chn;                                                     \
    /* issue next-chunk loads (independent of S) */                             \
    _Pragma("unroll")                                                           \
    for (int i4 = 0; i4 < 16; i4++) {                                           \
      float4 wv = *(const float4*)&Wbuf[cbn * 4096 + (size_t)lane * 64 + i4 * 4]; \
      WN[i4 * 4 + 0] = wv.x; WN[i4 * 4 + 1] = wv.y;                             \
      WN[i4 * 4 + 2] = wv.z; WN[i4 * 4 + 3] = wv.w;                             \
    }                                                                           \
    UVN = *(const float2*)&Ubuf[cbn * 4096 + (size_t)lane * 64 + c0];           \
    CUMN = cumbuf[cbn * 64 + lane];                                             \
    float4 knext[4];                                                            \
    _Pragma("unroll")                                                           \
    for (int n4 = 0; n4 < 4; n4++) {                                            \
      int n = tid + n4 * 256;                                                   \
      knext[n4] = *(const float4*)&khat[bhbase + (size_t)chn * 4096 + (size_t)n * 4]; \
    }                                                                           \
    /* compute current chunk */                                                 \
    float cum63 = rdlane(CUMC, 63);                                             \
    float sc = __expf(cum63 - CUMC);                                            \
    float Gend = __expf(cum63);                                                 \
    Sch[cb * 4096 + (size_t)(c0 + 0) * 64 + lane] = S0;                         \
    Sch[cb * 4096 + (size_t)(c0 + 1) * 64 + lane] = S1;                         \
    float a0 = 0.f, a1 = 0.f;                                                   \
    _Pragma("unroll")                                                           \
    for (int i = 0; i < 64; i++) {                                              \
      float s0 = rdlane(S0, i), s1 = rdlane(S1, i);                             \
      a0 += WC[i] * s0; a1 += WC[i] * s1;                                       \
    }                                                                           \
    float D0 = sc * (UVC.x - a0), D1 = sc * (UVC.y - a1);                       \
    float n0 = 0.f, n1 = 0.f;                                                   \
    _Pragma("unroll")                                                           \
    for (int t = 0; t < 64; t++) {                                              \
      float d0 = rdlane(D0, t), d1 = rdlane(D1, t);                             \
      float kk = Ksh[CUR][t * 68 + lane];                                       \
      n0 += kk * d0; n1 += kk * d1;                                             \
    }                                                                           \
    S0 = Gend * S0 + n0; S1 = Gend * S1 + n1;                                   \
    /* write next K buffer, one barrier per chunk */                            \
    _Pragma("unroll")                                                           \
    for (int n4 = 0; n4 < 4; n4++) {                                            \
      int n = tid + n4 * 256;                                                   \
      int row = n >> 4, col = (n & 15) * 4;                                     \
      *(float4*)&Ksh[NXT][row * 68 + col] = knext[n4];                          \
    }                                                                           \
    __syncthreads();                                                            \
  }

__global__ __launch_bounds__(256, 1) void k_chunkB(
    const float* __restrict__ khat, const float* __restrict__ cumbuf,
    const float* __restrict__ Ubuf, const float* __restrict__ Wbuf,
    float* __restrict__ Sch) {
  int bid = blockIdx.x;
  int bh = bid & 31, vb = bid >> 5;   // same-bh blocks -> same XCD (bid%8 const)
  int tid = threadIdx.x;
  int lane = tid & 63, q_ = tid >> 6;
  int c0 = vb * 8 + q_ * 2;
  __shared__ float Ksh[2][64 * 68];
  size_t bhbase = (size_t)bh * (2048 * 64);
  size_t cbb = (size_t)bh * 32;

  // prologue: chunk 0 operands
  float Wa[64], Wb[64];
  float2 uva, uvb;
  float cuma, cumb;
#pragma unroll
  for (int i4 = 0; i4 < 16; i4++) {
    float4 wv = *(const float4*)&Wbuf[cbb * 4096 + (size_t)lane * 64 + i4 * 4];
    Wa[i4 * 4 + 0] = wv.x; Wa[i4 * 4 + 1] = wv.y;
    Wa[i4 * 4 + 2] = wv.z; Wa[i4 * 4 + 3] = wv.w;
  }
  uva = *(const float2*)&Ubuf[cbb * 4096 + (size_t)lane * 64 + c0];
  cuma = cumbuf[cbb * 64 + lane];
  {
    float4 k0[4];
#pragma unroll
    for (int n4 = 0; n4 < 4; n4++) {
      int n = tid + n4 * 256;
      k0[n4] = *(const float4*)&khat[bhbase + (size_t)n * 4];
    }
#pragma unroll
    for (int n4 = 0; n4 < 4; n4++) {
      int n = tid + n4 * 256;
      int row = n >> 4, col = (n & 15) * 4;
      *(float4*)&Ksh[0][row * 68 + col] = k0[n4];
    }
  }
  __syncthreads();
  float S0 = 0.f, S1 = 0.f;
  for (int ch = 0; ch < 32; ch += 2) {
    CHUNK_STEP(ch, Wa, Wb, uva, uvb, cuma, cumb, 0, 1);
    CHUNK_STEP(ch + 1, Wb, Wa, uvb, uva, cumb, cuma, 1, 0);
  }
}
#undef CHUNK_STEP

// Phase C (parallel, 1024 blocks): O = diag(G) Q S_in + (QK^T . decaymask) Delta
__global__ __launch_bounds__(256) void k_out(
    const float* __restrict__ qhat, const float* __restrict__ khat,
    const float* __restrict__ cumbuf, const float* __restrict__ Ubuf,
    const float* __restrict__ Wbuf, const float* __restrict__ Sch,
    float* __restrict__ o_pre) {
  int bid = blockIdx.x;
  int bh = bid >> 5, ch = bid & 31;
  int b = bh >> 4, h = bh & 15;
  int tid = threadIdx.x;
  __shared__ float B1[64][65];  // W -> Q -> P
  __shared__ float B2[64][65];  // S -> K
  __shared__ float B3[64][65];  // Delta
  __shared__ float cumsh[64];
  size_t cb = (size_t)(bh * 32 + ch);
  size_t kbase = (size_t)bh * (2048 * 64) + (size_t)ch * 4096;
  if (tid < 64) cumsh[tid] = cumbuf[cb * 64 + tid];
  for (int idx = tid; idx < 4096; idx += 256) {
    B1[idx >> 6][idx & 63] = Wbuf[cb * 4096 + idx];
    B2[idx & 63][idx >> 6] = Sch[cb * 4096 + idx];   // Sch is column-major
  }
  __syncthreads();
  int t_ = tid & 63, q_ = tid >> 6;   // q_ 0..3 -> 16 cols each
  int c0 = q_ * 16;
  float acc[16], o1[16], p[16];
  // Delta = U - W S  -> B3
#pragma unroll
  for (int j = 0; j < 16; j++) acc[j] = 0.f;
  for (int i = 0; i < 64; i++) {
    float w = B1[t_][i];
#pragma unroll
    for (int j = 0; j < 16; j++) acc[j] += w * B2[i][c0 + j];
  }
#pragma unroll
  for (int j = 0; j < 16; j += 4) {
    float4 u = *(const float4*)&Ubuf[cb * 4096 + (size_t)t_ * 64 + c0 + j];
    B3[t_][c0 + j + 0] = u.x - acc[j + 0];
    B3[t_][c0 + j + 1] = u.y - acc[j + 1];
    B3[t_][c0 + j + 2] = u.z - acc[j + 2];
    B3[t_][c0 + j + 3] = u.w - acc[j + 3];
  }
  __syncthreads();
  // B1 <- Q
  for (int idx = tid; idx < 4096; idx += 256)
    B1[idx >> 6][idx & 63] = qhat[kbase + idx];
  __syncthreads();
  // O1 = Gt * (Q S)
#pragma unroll
  for (int j = 0; j < 16; j++) o1[j] = 0.f;
  for (int i = 0; i < 64; i++) {
    float qv = B1[t_][i];
#pragma unroll
    for (int j = 0; j < 16; j++) o1[j] += qv * B2[i][c0 + j];
  }
  {
    float Gt = __expf(cumsh[t_]);
#pragma unroll
    for (int j = 0; j < 16; j++) o1[j] *= Gt;
  }
  __syncthreads();
  // B2 <- K
  for (int idx = tid; idx < 4096; idx += 256)
    B2[idx >> 6][idx & 63] = khat[kbase + idx];
  __syncthreads();
  // P[t][s] = (q_t.k_s) exp(cum_t-cum_s), s<=t
#pragma unroll
  for (int m = 0; m < 16; m++) {
    int s = c0 + m;
    float d = 0.f;
    if (s <= t_) {
      for (int i = 0; i < 64; i++) d += B1[t_][i] * B2[s][i];
      d *= __expf(cumsh[t_] - cumsh[s]);
    }
    p[m] = d;
  }
  __syncthreads();
#pragma unroll
  for (int m = 0; m < 16; m++) B1[t_][c0 + m] = p[m];
  __syncthreads();
  // O = O1 + P Delta
  for (int s = 0; s < 64; s++) {
    float pv = B1[t_][s];
#pragma unroll
    for (int j = 0; j < 16; j++) o1[j] += pv * B3[s][c0 + j];
  }
  size_t ob = ((size_t)(b * 2048 + ch * 64 + t_)) * 1024 + h * 64 + c0;
#pragma unroll
  for (int j = 0; j < 16; j += 4) {
    float4 o4 = {o1[j], o1[j + 1], o1[j + 2], o1[j + 3]};
    *(float4*)&o_pre[ob + j] = o4;
  }
}

// ---------------------------------------------------------------------------
// epilogue: per-(m,h) RMSNorm(64, eps 1e-5, mean) * gnorm_w * silu(g) -> bf16
__global__ __launch_bounds__(256) void k_gatenorm(const float* __restrict__ o_pre,
    const float* __restrict__ g, const float* __restrict__ gnw,
    __bf16* __restrict__ obf) {
  int m = blockIdx.x;
  int tid = threadIdx.x;
  size_t baseo = (size_t)m * 1024 + tid * 4;
  float4 ov = *(const float4*)&o_pre[baseo];
  float ss = ov.x * ov.x + ov.y * ov.y + ov.z * ov.z + ov.w * ov.w;
  ss += __shfl_xor(ss, 1);
  ss += __shfl_xor(ss, 2);
  ss += __shfl_xor(ss, 4);
  ss += __shfl_xor(ss, 8);
  float inv = rsqrtf(ss * (1.f / 64.f) + 1e-5f);
  float4 gv = *(const float4*)&g[baseo];
  int d0 = (tid & 15) * 4;
  float r0 = ov.x * inv * gnw[d0 + 0] * (gv.x * (1.f / (1.f + __expf(-gv.x))));
  float r1 = ov.y * inv * gnw[d0 + 1] * (gv.y * (1.f / (1.f + __expf(-gv.y))));
  float r2 = ov.z * inv * gnw[d0 + 2] * (gv.z * (1.f / (1.f + __expf(-gv.z))));
  float r3 = ov.w * inv * gnw[d0 + 3] * (gv.w * (1.f / (1.f + __expf(-gv.w))));
  bf16x4 o;
  o.x = (__bf16)r0; o.y = (__bf16)r1; o.z = (__bf16)r2; o.w = (__bf16)r3;
  *(bf16x4*)&obf[baseo] = o;
}

// ---------------------------------------------------------------------------
extern "C" void kernel_launch(void* const* d_in, const int* in_sizes, int n_in,
                              void* d_out, int out_size, void* d_ws, size_t ws_size,
                              hipStream_t stream) {
  const float* x = (const float*)d_in[0];
  const float* Wq = (const float*)d_in[1];
  const float* Wk = (const float*)d_in[2];
  const float* Wv = (const float*)d_in[3];
  const float* Wo = (const float*)d_in[4];
  const float* Wg = (const float*)d_in[5];
  const float* Wgk = (const float*)d_in[6];
  const float* Wb = (const float*)d_in[7];
  const float* bb = (const float*)d_in[8];
  const float* A_log = (const float*)d_in[9];
  const float* cqw = (const float*)d_in[10];
  const float* ckw = (const float*)d_in[11];
  const float* cvw = (const float*)d_in[12];
  const float* gnw = (const float*)d_in[13];
  const float* dtb = (const float*)d_in[14];
  float* out = (float*)d_out;

  char* ws = (char*)d_ws;
  __bf16* xbf   = (__bf16*)(ws + 0);            // 8 MB  (later obf)
  __bf16* wq_t  = (__bf16*)(ws + 8388608);      // 2 MB  (later cumbuf)
  __bf16* wk_t  = (__bf16*)(ws + 10485760);
  __bf16* wv_t  = (__bf16*)(ws + 12582912);
  __bf16* wg_t  = (__bf16*)(ws + 14680064);
  __bf16* wo_t  = (__bf16*)(ws + 16777216);
  float* qpre   = (float*)(ws + 18874368);      // 16 MB (later o_pre)
  float* kpre   = (float*)(ws + 35651584);      // 16 MB (later Ubuf)
  float* vpre   = (float*)(ws + 52428800);      // 16 MB (later Wbuf)
  float* gbuf   = (float*)(ws + 69206016);
  float* qhat   = (float*)(ws + 85983232);
  float* khat   = (float*)(ws + 102760448);
  float* vhat   = (float*)(ws + 119537664);     // 16 MB (later Sch)
  float* gk_arr = (float*)(ws + 136314880);     // 256 KB
  float* beta_a = (float*)(ws + 136577024);     // 256 KB
  float* o_pre  = qpre;
  __bf16* obf   = xbf;
  float* cumbuf = (float*)wq_t;   // 256 KB, wq_t dead after big gemm
  float* Ubuf   = kpre;           // kpre dead after conv
  float* Wbuf   = vpre;           // vpre dead after conv
  float* Sch    = vhat;           // vhat dead after chunkA
  // gk/beta projection staging — both live only between gemm and conv:
  __bf16* wgb_t = (__bf16*)khat;  // 256 KB in khat region (conv writes after)
  float* pbuf   = qhat;           // 2 MB in qhat region   (conv writes after)

  k_convert<<<dim3((NM * NC / 4 + 255) / 256), 256, 0, stream>>>(x, xbf, NM * NC / 4);
  dim3 tg(16, 16);
  k_transpose<<<tg, 256, 0, stream>>>(Wq, wq_t);
  k_transpose<<<tg, 256, 0, stream>>>(Wk, wk_t);
  k_transpose<<<tg, 256, 0, stream>>>(Wv, wv_t);
  k_transpose<<<tg, 256, 0, stream>>>(Wg, wg_t);
  k_transpose<<<tg, 256, 0, stream>>>(Wo, wo_t);
  k_buildwgb<<<16, 256, 0, stream>>>(Wgk, Wb, wgb_t);
  // fused q/k/v/g + gk/beta projections (grid.y = 4*8 + 1)
  k_gemm<<<dim3(NM / 128, 33), 256, 0, stream>>>(xbf, wq_t, wk_t, wv_t, wg_t, wgb_t,
                                                 qpre, kpre, vpre, gbuf, pbuf, 8);
  k_projpost<<<NM * 32 / 256, 256, 0, stream>>>(pbuf, bb, A_log, dtb, gk_arr, beta_a);
  k_conv<<<dim3(NT / 64, NB * NH, 3), 256, 0, stream>>>(qpre, kpre, vpre, cqw, ckw,
                                                        cvw, qhat, khat, vhat);
  // chunked gated-delta scan
  k_chunkA<<<1024, 256, 0, stream>>>(khat, vhat, gk_arr, beta_a, cumbuf, Ubuf, Wbuf);
  k_chunkB<<<256, 256, 0, stream>>>(khat, cumbuf, Ubuf, Wbuf, Sch);
  k_out<<<1024, 256, 0, stream>>>(qhat, khat, cumbuf, Ubuf, Wbuf, Sch, o_pre);
  k_gatenorm<<<NM, 256, 0, stream>>>(o_pre, gbuf, gnw, obf);
  k_gemm<<<dim3(NM / 128, 8), 256, 0, stream>>>(obf, wo_t, nullptr, nullptr, nullptr,
                                                nullptr, out, nullptr, nullptr, nullptr,
                                                nullptr, 8);
}